// Round 10
// baseline (30.706 us; speedup 1.0000x reference)
//
#include <hip/hip_runtime.h>
#include <math.h>

namespace {
constexpr int NB   = 256;
constexpr int NA   = 64;
constexpr int EMBD = 64;
constexpr int HIDD = 128;
constexpr int OUTD = 512;
constexpr int FPS  = 136;  // short-stride for bf16 LDS tiles (272 B rows)

// ws float layout: [0,65536) Wf = W2@Wo ; [65536,66048) outb = b2@Wo+bo ;
// shorts at wsf+66048: W1-hi MFMA B-fragments (16384 shorts = 32 KB)
constexpr int WS_WF   = 0;
constexpr int WS_OUTB = 65536;
constexpr int WS_FRAG = 66048;   // float offset; *4 bytes = 16-aligned

typedef __attribute__((ext_vector_type(8))) short bfrag8;
typedef __attribute__((ext_vector_type(4))) float floatx4;

__device__ __forceinline__ unsigned short bf16_rne(float f) {
    unsigned u = __float_as_uint(f);
    u += 0x7fffu + ((u >> 16) & 1u);
    return (unsigned short)(u >> 16);
}

// branch-free exact-GELU: erf via Abramowitz-Stegun 7.1.26 (|err| <= 1.5e-7)
__device__ __forceinline__ float gelu_fast(float x) {
    const float ax = fabsf(x) * 0.7071067811865475f;
    const float t  = __builtin_amdgcn_rcpf(fmaf(0.3275911f, ax, 1.0f));
    float p = fmaf(1.061405429f, t, -1.453152027f);
    p = fmaf(p, t, 1.421413741f);
    p = fmaf(p, t, -0.284496736f);
    p = fmaf(p, t, 0.254829592f);
    p = p * t;
    const float e = __builtin_amdgcn_exp2f(-1.4426950408889634f * ax * ax);
    const float erfx = copysignf(fmaf(-p, e, 1.0f), x);
    const float hx   = 0.5f * x;
    return fmaf(hx, erfx, hx);
}

// ---- prep: Wf = W2@Wo, outb = b2@Wo+bo, W1-hi frags, zero d_out.
__global__ __launch_bounds__(512, 2)
void prep(const float* __restrict__ W1, const float* __restrict__ W2,
          const float* __restrict__ b2, const float* __restrict__ Wo,
          const float* __restrict__ bo, float* __restrict__ wsf,
          float* __restrict__ out) {
    const int bid = blockIdx.x;      // 128 blocks
    const int tid = threadIdx.x;     // 512

    // Wf row k = bid
    {
        const float* w2row = W2 + (size_t)bid * HIDD;
        float acc = 0.0f;
#pragma unroll 8
        for (int j = 0; j < HIDD; ++j)
            acc = fmaf(w2row[j], Wo[(size_t)j * OUTD + tid], acc);
        wsf[WS_WF + bid * OUTD + tid] = acc;
    }
    // outb (block 0)
    if (bid == 0) {
        float a = bo[tid];
#pragma unroll 8
        for (int j = 0; j < HIDD; ++j)
            a = fmaf(b2[j], Wo[(size_t)j * OUTD + tid], a);
        wsf[WS_OUTB + tid] = a;
    }
    // W1-hi fragments (blocks 32..63): f = (fg*64+ls)*8+r
    if (bid >= 32 && bid < 64) {
        const int f  = ((bid - 32) << 9) + tid;
        const int fg = f >> 9, ls = (f >> 3) & 63, r = f & 7;
        const int k  = ((fg >> 3) << 5) + ((ls >> 4) << 3) + r;
        const int n  = ((fg & 7) << 4) + (ls & 15);
        ((short*)(wsf + WS_FRAG))[f] = (short)bf16_rne(W1[(size_t)k * HIDD + n]);
    }
    // zero d_out (atomicAdd accumulation target; re-zeroed every replay)
    out[(size_t)bid * OUTD + tid]         = 0.0f;
    out[(size_t)(bid + 128) * OUTD + tid] = 0.0f;
}

// ---- main: 512 blocks (mol = bid>>1, half h = bid&1), 512 threads, 2 blocks/CU
__global__ __launch_bounds__(512, 4)
void mlip_half(const int*   __restrict__ atomic_nums,
               const float* __restrict__ coords,
               const float* __restrict__ embed_table,
               const float* __restrict__ b1,
               const float* __restrict__ centers,
               const float* __restrict__ wsf,
               float*       __restrict__ out)
{
    const int bid  = blockIdx.x;
    const int mol  = bid >> 1;
    const int h    = bid & 1;
    const int tid  = threadIdx.x;
    const int lane = tid & 63;
    const int wid  = tid >> 6;        // 8 waves

    __shared__ float s_c[NA * 3];                      // 768 B coords
    __shared__ short s_w1h[16384];                     // 32 KB W1-hi frags
    __shared__ short s_fhi[32][FPS], s_flo[32][FPS];   // 17.4 KB feat (32 rows)
    __shared__ float s_mol[2][HIDD];                   // per-wm col sums
    __shared__ float s_molv[HIDD];

    // ---- tiling ids (8 waves = 2 wm x 4 wn; each wave 16 rows x 32 cols)
    const int wm      = wid & 1, wn = wid >> 1;
    const int lrow    = lane & 15, g4 = lane >> 4;
    const int arow    = (wm << 4) + lrow;              // local row 0..31
    const int colbase = (wn << 5) + lrow;

    // ---- gauss ids: thread = (local row, g-chunk, j-quarter)
    const int grow = tid >> 4;        // 0..31
    const int gch  = (tid >> 2) & 3;
    const int jq   = tid & 3;

    const float b1a = b1[colbase];
    const float b1b = b1[colbase + 16];
    const float c0  = centers[gch << 4];

    // ---- stage coords (48 float4), W1 frags (4 uint4/thread), embedding
    if (tid < 48)
        *(float4*)&s_c[tid << 2] = *(const float4*)(coords + (size_t)mol * 192 + (tid << 2));
    {
        const uint4* fsrc = (const uint4*)(wsf + WS_FRAG);
        uint4* fdst = (uint4*)s_w1h;
#pragma unroll
        for (int a = 0; a < 4; ++a) {
            const int idx = (a << 9) + tid;
            fdst[idx] = fsrc[idx];
        }
    }
    {
        const int row = tid >> 4, e4 = (tid & 15) << 2;
        const int gr  = (h << 5) + row;
        const int z   = atomic_nums[mol * NA + gr];
        const float4 ev = *(const float4*)(embed_table + (size_t)z * EMBD + e4);
        short4 h4, l4;
        const float v[4] = {ev.x, ev.y, ev.z, ev.w};
        short* hp = (short*)&h4; short* lp = (short*)&l4;
#pragma unroll
        for (int q = 0; q < 4; ++q) {
            const unsigned short hh = bf16_rne(v[q]);
            hp[q] = (short)hh;
            lp[q] = (short)bf16_rne(v[q] - __uint_as_float((unsigned)hh << 16));
        }
        *(short4*)&s_fhi[row][e4] = h4;
        *(short4*)&s_flo[row][e4] = l4;
    }
    __syncthreads();                                   // bar0: coords ready

    // ---- gauss: dists computed inline from coords; geometric recurrence
    // t_g = exp(-2(d-c_g)^2); t_{g+1} = t_g*u; u *= WF (scalar chain, R8-proven)
    {
        constexpr float L2E   = 1.4426950408889634f;
        constexpr float DELTA = 10.0f / 63.0f;
        constexpr float K2L   = -2.0f * L2E;
        constexpr float UA    = 4.0f * DELTA * L2E;
        constexpr float UB    = -2.0f * DELTA * DELTA * L2E;
        constexpr float WF    = 0.9041312f;            // exp(-4*DELTA^2)

        const int   gr  = (h << 5) + grow;
        const float cxr = s_c[gr * 3 + 0];
        const float cyr = s_c[gr * 3 + 1];
        const float czr = s_c[gr * 3 + 2];

        float acc[16];
#pragma unroll
        for (int q = 0; q < 16; ++q) acc[q] = 0.0f;

#pragma unroll 4
        for (int jj = 0; jj < 16; ++jj) {
            const int j = (jq << 4) + jj;
            const float dx = cxr - s_c[j * 3 + 0];
            const float dy = cyr - s_c[j * 3 + 1];
            const float dz = czr - s_c[j * 3 + 2];
            const float sq = dx * dx + dy * dy + dz * dz;
            const float d  = sq > 0.0f ? sqrtf(sq) : 0.0f;
            const float x  = d - c0;
            float t = __builtin_amdgcn_exp2f(K2L * x * x);
            float u = __builtin_amdgcn_exp2f(fmaf(UA, x, UB));
#pragma unroll
            for (int q = 0; q < 15; ++q) { acc[q] += t; t *= u; u *= WF; }
            acc[15] += t;
        }
        // reduce over j-quarters (lane bits 0-1)
#pragma unroll
        for (int q = 0; q < 16; ++q) {
            acc[q] += __shfl_xor(acc[q], 1, 64);
            acc[q] += __shfl_xor(acc[q], 2, 64);
        }
        if (jq == 0) {
            unsigned* hp = (unsigned*)&s_fhi[grow][EMBD + (gch << 4)];
            unsigned* lp = (unsigned*)&s_flo[grow][EMBD + (gch << 4)];
#pragma unroll
            for (int q2 = 0; q2 < 8; ++q2) {
                const float v0 = acc[2 * q2]     * (1.0f / 64.0f);
                const float v1 = acc[2 * q2 + 1] * (1.0f / 64.0f);
                const unsigned h0 = bf16_rne(v0), h1 = bf16_rne(v1);
                const unsigned l0 = bf16_rne(v0 - __uint_as_float(h0 << 16));
                const unsigned l1 = bf16_rne(v1 - __uint_as_float(h1 << 16));
                hp[q2] = h0 | (h1 << 16);
                lp[q2] = l0 | (l1 << 16);
            }
        }
    }
    __syncthreads();                                   // bar1: feat + W1 ready

    // ---- GEMM1 (2-term: Ahi*Bhi + Alo*Bhi); gelu; col-sums
    {
        floatx4 acc0 = {0,0,0,0}, acc1 = {0,0,0,0};
#pragma unroll
        for (int ks = 0; ks < 4; ++ks) {
            const int k0 = (ks << 5) + (g4 << 3);
            const bfrag8 ahi = *(const bfrag8*)&s_fhi[arow][k0];
            const bfrag8 alo = *(const bfrag8*)&s_flo[arow][k0];
#pragma unroll
            for (int nt = 0; nt < 2; ++nt) {
                const int fidx = (((ks << 3) + (wn << 1) + nt) << 6) + lane;
                const bfrag8 bhi = *(const bfrag8*)&s_w1h[fidx << 3];
                floatx4 a = nt ? acc1 : acc0;
                a = __builtin_amdgcn_mfma_f32_16x16x32_bf16(ahi, bhi, a, 0, 0, 0);
                a = __builtin_amdgcn_mfma_f32_16x16x32_bf16(alo, bhi, a, 0, 0, 0);
                if (nt) acc1 = a; else acc0 = a;
            }
        }
#pragma unroll
        for (int nt = 0; nt < 2; ++nt) {
            const float bb = nt ? b1b : b1a;
            const floatx4 a = nt ? acc1 : acc0;
            float s = gelu_fast(a[0] + bb) + gelu_fast(a[1] + bb)
                    + gelu_fast(a[2] + bb) + gelu_fast(a[3] + bb);
            s += __shfl_xor(s, 16, 64);
            s += __shfl_xor(s, 32, 64);
            if (lane < 16) s_mol[wm][colbase + (nt << 4)] = s;
        }
    }
    __syncthreads();                                   // bar2: s_mol ready

    if (tid < HIDD)
        s_molv[tid] = (s_mol[0][tid] + s_mol[1][tid]) * (1.0f / 64.0f);
    __syncthreads();                                   // bar3: molv ready

    // ---- tail: partial out = molv @ Wf (+ outb for h==0); atomicAdd combine
    {
        const float* wf = wsf + WS_WF + tid;           // col = tid
        float a = (h == 0) ? wsf[WS_OUTB + tid] : 0.0f;
#pragma unroll 8
        for (int k = 0; k < HIDD; ++k)
            a = fmaf(s_molv[k], wf[(size_t)k << 9], a);
        atomicAdd(out + (size_t)mol * OUTD + tid, a);
    }
}
} // namespace

extern "C" void kernel_launch(void* const* d_in, const int* in_sizes, int n_in,
                              void* d_out, int out_size, void* d_ws, size_t ws_size,
                              hipStream_t stream) {
    const int*   atomic_nums = (const int*)  d_in[0];
    const float* coords      = (const float*)d_in[1];
    const float* embed_table = (const float*)d_in[2];
    const float* W1          = (const float*)d_in[3];
    const float* b1          = (const float*)d_in[4];
    const float* W2          = (const float*)d_in[5];
    const float* b2          = (const float*)d_in[6];
    const float* Wo          = (const float*)d_in[7];
    const float* bo          = (const float*)d_in[8];
    const float* centers     = (const float*)d_in[9];
    float*       out         = (float*)d_out;
    float*       wsf         = (float*)d_ws;   // needs ~300 KB

    prep<<<128, 512, 0, stream>>>(W1, W2, b2, Wo, bo, wsf, out);
    mlip_half<<<2 * NB, 512, 0, stream>>>(atomic_nums, coords, embed_table,
                                          b1, centers, wsf, out);
}

// Round 11
// 25.010 us; speedup vs baseline: 1.2277x; 1.2277x over previous
//
#include <hip/hip_runtime.h>
#include <math.h>

namespace {
constexpr int NB   = 256;
constexpr int NA   = 64;
constexpr int EMBD = 64;
constexpr int HIDD = 128;
constexpr int OUTD = 512;
constexpr int FPS  = 136;  // short-stride for bf16 LDS tiles (272 B rows: conflict-free frag reads)
constexpr int DSTR = 68;   // padded float-stride for s_dist (gauss reads land 2-way banks = free)

typedef __attribute__((ext_vector_type(8))) short bfrag8;   // 8 bf16 = 4 VGPRs
typedef __attribute__((ext_vector_type(4))) float floatx4;  // MFMA accumulator

__device__ __forceinline__ unsigned short bf16_rne(float f) {
    unsigned u = __float_as_uint(f);
    u += 0x7fffu + ((u >> 16) & 1u);
    return (unsigned short)(u >> 16);
}

// branch-free exact-GELU: erf via Abramowitz-Stegun 7.1.26 (|err| <= 1.5e-7)
__device__ __forceinline__ float gelu_fast(float x) {
    const float ax = fabsf(x) * 0.7071067811865475f;
    const float t  = __builtin_amdgcn_rcpf(fmaf(0.3275911f, ax, 1.0f));
    float p = fmaf(1.061405429f, t, -1.453152027f);
    p = fmaf(p, t, 1.421413741f);
    p = fmaf(p, t, -0.284496736f);
    p = fmaf(p, t, 0.254829592f);
    p = p * t;
    const float e = __builtin_amdgcn_exp2f(-1.4426950408889634f * ax * ax);
    const float erfx = copysignf(fmaf(-p, e, 1.0f), x);
    const float hx   = 0.5f * x;
    return fmaf(hx, erfx, hx);
}

// W1-fragment LDS layout (shorts, hi only): (fg*64+ls)*8 + r,
// fg = ks*8 + tile;  element = W1[ks*32+(ls>>4)*8+r][tile*16+(ls&15)]
// 2-term split GEMM1: A(hi+lo) x B(hi) — B-lo dropped (R10-measured absmax 3.9e-3)

__global__ __launch_bounds__(1024, 1)
void mlip_fused(const int*   __restrict__ atomic_nums,
                const float* __restrict__ coords,
                const float* __restrict__ embed_table,
                const float* __restrict__ W1, const float* __restrict__ b1,
                const float* __restrict__ W2, const float* __restrict__ b2,
                const float* __restrict__ Wo, const float* __restrict__ bo,
                const float* __restrict__ centers,
                float*       __restrict__ out)
{
    const int b    = blockIdx.x;
    const int tid  = threadIdx.x;
    const int lane = tid & 63;
    const int wid  = tid >> 6;          // 16 waves

    __shared__ float s_dist[NA * DSTR];                // 17 KB; reused as GEMV partial buf
    __shared__ short s_w[16384];                       // 32 KB: W1 frags (hi only)
    __shared__ short s_fhi[NA][FPS], s_flo[NA][FPS];   // feat bf16 hi/lo (34 KB)
    __shared__ float s_mol[4][HIDD];                   // per-wm column sums of gelu out
    __shared__ float s_molv[HIDD];

    // ---- tiling ids
    const int wm      = wid & 3, wn = wid >> 2;
    const int lrow    = lane & 15, g4 = lane >> 4;
    const int arow    = (wm << 4) + lrow;
    const int colbase = (wn << 5) + lrow;

    // ---- GEMV ids + tail ids
    const int gcol = tid & 127, kc = tid >> 7;         // kc in [0,8)
    const int colT = tid >> 1, kh = tid & 1;

    // ---- gauss recurrence ids: thread = (row, g-chunk, j-quarter)
    const int grow = tid >> 4;          // row i in [0,64)
    const int gch  = (tid >> 2) & 3;    // 16-center chunk
    const int jq   = tid & 3;           // 16-j quarter

    // ---- small preloads
    const float bo_r = bo[colT];
    const float b1a  = b1[colbase];
    const float b1b  = b1[colbase + 16];
    const float b2r  = b2[gcol];
    const float c0   = centers[gch << 4];   // chunk base center (input-exact)

    // ---- issue W1 loads early (indices recomputed inline)
    float w1v[16];
#pragma unroll
    for (int a = 0; a < 2; ++a) {
        const int slot = (a << 10) + tid;
        const int fg = slot >> 6, ls = slot & 63;
        const int k0 = ((fg >> 3) << 5) + ((ls >> 4) << 3);
        const int n  = ((fg & 7) << 4) + (ls & 15);
        const float* src = W1 + (size_t)k0 * HIDD + n;
#pragma unroll
        for (int r = 0; r < 8; ++r) w1v[a * 8 + r] = src[(size_t)r * HIDD];
    }

    // ---- coords + embedding
    const float* cbase = coords + (size_t)b * NA * 3;
    const float cx = cbase[lane * 3 + 0];
    const float cy = cbase[lane * 3 + 1];
    const float cz = cbase[lane * 3 + 2];
    {
        const int i = tid >> 4, e4 = (tid & 15) << 2;
        const int z = atomic_nums[b * NA + i];
        const float4 ev = *(const float4*)(embed_table + (size_t)z * EMBD + e4);
        short4 h4, l4;
        const float v[4] = {ev.x, ev.y, ev.z, ev.w};
        short* hp = (short*)&h4; short* lp = (short*)&l4;
#pragma unroll
        for (int q = 0; q < 4; ++q) {
            const unsigned short h = bf16_rne(v[q]);
            hp[q] = (short)h;
            lp[q] = (short)bf16_rne(v[q] - __uint_as_float((unsigned)h << 16));
        }
        *(short4*)&s_fhi[i][e4] = h4;
        *(short4*)&s_flo[i][e4] = l4;
    }

    // ---- pairwise distances: wave w writes rows 4w..4w+3 — exactly the rows its
    // own gauss threads (grow = tid>>4) read  =>  within-wave dep, no barrier
#pragma unroll
    for (int it = 0; it < 4; ++it) {
        const int i = (wid << 2) + it;
        const float xi = __shfl(cx, i, 64);
        const float yi = __shfl(cy, i, 64);
        const float zi = __shfl(cz, i, 64);
        const float dx = xi - cx, dy = yi - cy, dz = zi - cz;
        const float sq = dx * dx + dy * dy + dz * dz;
        s_dist[i * DSTR + lane] = sq > 0.0f ? sqrtf(sq) : 0.0f;
    }

    // ---- convert W1 -> s_w (hi only, b128 stores); w1v dies here
#pragma unroll
    for (int a = 0; a < 2; ++a) {
        unsigned Hu[4];
#pragma unroll
        for (int p = 0; p < 4; ++p) {
            const float x = w1v[a * 8 + 2 * p], y = w1v[a * 8 + 2 * p + 1];
            unsigned h;
            asm("v_cvt_pk_bf16_f32 %0, %1, %2" : "=v"(h) : "v"(x), "v"(y));
            Hu[p] = h;
        }
        const int slot = (a << 10) + tid;
        const int base = ((slot >> 6) << 9) + (slot & 63) * 8;
        *(uint4*)&s_w[base] = make_uint4(Hu[0], Hu[1], Hu[2], Hu[3]);
    }

    // ---- gaussian smear via geometric recurrence (R8-proven scalar chain):
    // t_g = exp(-2(d-c_g)^2);  t_{g+1} = t_g*u;  u *= WF (const).
    {
        constexpr float L2E   = 1.4426950408889634f;
        constexpr float DELTA = 10.0f / 63.0f;
        constexpr float K2L   = -2.0f * L2E;
        constexpr float UA    = 4.0f * DELTA * L2E;
        constexpr float UB    = -2.0f * DELTA * DELTA * L2E;
        constexpr float WF    = 0.9041312f;              // exp(-4*DELTA^2)

        float acc[16];
#pragma unroll
        for (int q = 0; q < 16; ++q) acc[q] = 0.0f;

        const float* drow = &s_dist[grow * DSTR + (jq << 4)];
#pragma unroll
        for (int j4 = 0; j4 < 4; ++j4) {
            const float4 d4 = *(const float4*)(drow + (j4 << 2));
            const float dv[4] = {d4.x, d4.y, d4.z, d4.w};
#pragma unroll
            for (int jj = 0; jj < 4; ++jj) {
                const float x = dv[jj] - c0;
                float t = __builtin_amdgcn_exp2f(K2L * x * x);
                float u = __builtin_amdgcn_exp2f(fmaf(UA, x, UB));
#pragma unroll
                for (int q = 0; q < 15; ++q) { acc[q] += t; t *= u; u *= WF; }
                acc[15] += t;
            }
        }
        // reduce over j-quarters (lane bits 0-1)
#pragma unroll
        for (int q = 0; q < 16; ++q) {
            acc[q] += __shfl_xor(acc[q], 1, 64);
            acc[q] += __shfl_xor(acc[q], 2, 64);
        }
        if (jq == 0) {
            unsigned* hp = (unsigned*)&s_fhi[grow][EMBD + (gch << 4)];
            unsigned* lp = (unsigned*)&s_flo[grow][EMBD + (gch << 4)];
#pragma unroll
            for (int q2 = 0; q2 < 8; ++q2) {
                const float v0 = acc[2 * q2]     * (1.0f / 64.0f);
                const float v1 = acc[2 * q2 + 1] * (1.0f / 64.0f);
                const unsigned h0 = bf16_rne(v0), h1 = bf16_rne(v1);
                const unsigned l0 = bf16_rne(v0 - __uint_as_float(h0 << 16));
                const unsigned l1 = bf16_rne(v1 - __uint_as_float(h1 << 16));
                hp[q2] = h0 | (h1 << 16);
                lp[q2] = l0 | (l1 << 16);
            }
        }
    }
    __syncthreads();                                   // barrier 1: feat + W1 frags ready

    // ---- stage 3: G = gelu(feat @ W1 + b1); 2-term MFMA; col-sums folded in-register
    float wo_a[32];
    float w2r[16];
    {
        floatx4 acc0 = {0,0,0,0}, acc1 = {0,0,0,0};
#pragma unroll
        for (int ks = 0; ks < 4; ++ks) {
            const int k0 = (ks << 5) + (g4 << 3);
            const bfrag8 ahi = *(const bfrag8*)&s_fhi[arow][k0];
            const bfrag8 alo = *(const bfrag8*)&s_flo[arow][k0];
#pragma unroll
            for (int nt = 0; nt < 2; ++nt) {
                const int base = ((((ks << 3) + (wn << 1) + nt) << 6) + lane) << 3;
                const bfrag8 bhi = *(const bfrag8*)&s_w[base];
                floatx4 a = nt ? acc1 : acc0;
                a = __builtin_amdgcn_mfma_f32_16x16x32_bf16(ahi, bhi, a, 0, 0, 0);
                a = __builtin_amdgcn_mfma_f32_16x16x32_bf16(alo, bhi, a, 0, 0, 0);
                if (nt) acc1 = a; else acc0 = a;
            }
        }

        // issue first Wo half + W2 GEMV rows (hidden under gelu/reduce/barrier)
        {
            const float* wop = Wo + ((size_t)(kh << 6)) * OUTD + colT;
#pragma unroll
            for (int k = 0; k < 32; ++k) wo_a[k] = wop[(size_t)k * OUTD];
            const float* src = W2 + (size_t)(kc << 4) * HIDD + gcol;
#pragma unroll
            for (int q = 0; q < 16; ++q) w2r[q] = src[(size_t)q * HIDD];
        }

        // gelu + column reduce: rows g4*4+r summed in-lane, then across g4 groups
#pragma unroll
        for (int nt = 0; nt < 2; ++nt) {
            const float bb = nt ? b1b : b1a;
            const floatx4 a = nt ? acc1 : acc0;
            float s = gelu_fast(a[0] + bb) + gelu_fast(a[1] + bb)
                    + gelu_fast(a[2] + bb) + gelu_fast(a[3] + bb);
            s += __shfl_xor(s, 16, 64);
            s += __shfl_xor(s, 32, 64);
            if (lane < 16) s_mol[wm][colbase + (nt << 4)] = s;   // col-sum of 16 rows
        }
    }
    __syncthreads();                                   // barrier 2: s_mol ready

    // ---- GEMV: mol_raw[col] = sum_k (sum_wm s_mol[wm][k]) * W2[k][col]
    float wo_b[32];
    {
        float acc = 0.0f;
        const int kb = kc << 4;
#pragma unroll
        for (int q = 0; q < 16; ++q) {
            const int k = kb + q;
            const float hk = (s_mol[0][k] + s_mol[1][k])
                           + (s_mol[2][k] + s_mol[3][k]);   // wave-uniform broadcasts
            acc = fmaf(hk, w2r[q], acc);
        }
        s_dist[(kc << 7) + gcol] = acc;                // s_dist reused as partial buf

        // issue second Wo half (hidden under barrier 3 + reduce + barrier 4)
        const float* wop = Wo + ((size_t)((kh << 6) + 32)) * OUTD + colT;
#pragma unroll
        for (int k = 0; k < 32; ++k) wo_b[k] = wop[(size_t)k * OUTD];
    }
    __syncthreads();                                   // barrier 3: partials ready

    // ---- mol = colsum/64 + b2
    if (tid < HIDD) {
        float m = 0.0f;
#pragma unroll
        for (int p = 0; p < 8; ++p) m += s_dist[(p << 7) + tid];
        s_molv[tid] = m * (1.0f / 64.0f) + b2r;
    }
    __syncthreads();                                   // barrier 4: molv ready

    // ---- tail: out = mol @ Wo + bo; lane-pair K-split, shfl combine
    {
        const float* mp = &s_molv[kh << 6];
        float a = 0.0f;
#pragma unroll
        for (int k = 0; k < 32; ++k) a = fmaf(mp[k], wo_a[k], a);
#pragma unroll
        for (int k = 0; k < 32; ++k) a = fmaf(mp[32 + k], wo_b[k], a);
        a += __shfl_xor(a, 1, 64);
        if (kh == 0)
            out[(size_t)b * OUTD + colT] = a + bo_r;
    }
}
} // namespace

extern "C" void kernel_launch(void* const* d_in, const int* in_sizes, int n_in,
                              void* d_out, int out_size, void* d_ws, size_t ws_size,
                              hipStream_t stream) {
    const int*   atomic_nums = (const int*)  d_in[0];
    const float* coords      = (const float*)d_in[1];
    const float* embed_table = (const float*)d_in[2];
    const float* W1          = (const float*)d_in[3];
    const float* b1          = (const float*)d_in[4];
    const float* W2          = (const float*)d_in[5];
    const float* b2          = (const float*)d_in[6];
    const float* Wo          = (const float*)d_in[7];
    const float* bo          = (const float*)d_in[8];
    const float* centers     = (const float*)d_in[9];
    float*       out         = (float*)d_out;

    mlip_fused<<<NB, 1024, 0, stream>>>(atomic_nums, coords, embed_table,
                                        W1, b1, W2, b2, Wo, bo, centers, out);
}

// Round 12
// 22.784 us; speedup vs baseline: 1.3477x; 1.0977x over previous
//
#include <hip/hip_runtime.h>
#include <math.h>

namespace {
constexpr int NB   = 256;
constexpr int NA   = 64;
constexpr int EMBD = 64;
constexpr int HIDD = 128;
constexpr int OUTD = 512;
constexpr int FPS  = 136;  // short-stride for bf16 LDS tiles (272 B rows: conflict-free frag reads)
constexpr int DSTR = 68;   // padded float-stride for s_dist (gauss reads land 2-way banks = free)

typedef __attribute__((ext_vector_type(8))) short bfrag8;   // 8 bf16 = 4 VGPRs
typedef __attribute__((ext_vector_type(4))) float floatx4;  // MFMA accumulator

__device__ __forceinline__ unsigned short bf16_rne(float f) {
    unsigned u = __float_as_uint(f);
    u += 0x7fffu + ((u >> 16) & 1u);
    return (unsigned short)(u >> 16);
}

// branch-free exact-GELU: erf via Abramowitz-Stegun 7.1.26 (|err| <= 1.5e-7)
__device__ __forceinline__ float gelu_fast(float x) {
    const float ax = fabsf(x) * 0.7071067811865475f;
    const float t  = __builtin_amdgcn_rcpf(fmaf(0.3275911f, ax, 1.0f));
    float p = fmaf(1.061405429f, t, -1.453152027f);
    p = fmaf(p, t, 1.421413741f);
    p = fmaf(p, t, -0.284496736f);
    p = fmaf(p, t, 0.254829592f);
    p = p * t;
    const float e = __builtin_amdgcn_exp2f(-1.4426950408889634f * ax * ax);
    const float erfx = copysignf(fmaf(-p, e, 1.0f), x);
    const float hx   = 0.5f * x;
    return fmaf(hx, erfx, hx);
}

// W1-fragment LDS layout (shorts, hi only): (fg*64+ls)*8 + r,
// fg = ks*8 + tile;  element = W1[ks*32+(ls>>4)*8+r][tile*16+(ls&15)]
// 2-term split GEMM1: A(hi+lo) x B(hi) — B-lo dropped (R10-measured absmax 3.9e-3)

__global__ __launch_bounds__(1024, 1)
void mlip_fused(const int*   __restrict__ atomic_nums,
                const float* __restrict__ coords,
                const float* __restrict__ embed_table,
                const float* __restrict__ W1, const float* __restrict__ b1,
                const float* __restrict__ W2, const float* __restrict__ b2,
                const float* __restrict__ Wo, const float* __restrict__ bo,
                const float* __restrict__ centers,
                float*       __restrict__ out)
{
    const int b    = blockIdx.x;
    const int tid  = threadIdx.x;
    const int lane = tid & 63;
    const int wid  = tid >> 6;          // 16 waves

    __shared__ float s_dist[NA * DSTR];                // 17 KB; reused as GEMV partial buf
    __shared__ short s_w[16384];                       // 32 KB: W1 frags (hi only)
    __shared__ short s_fhi[NA][FPS], s_flo[NA][FPS];   // feat bf16 hi/lo (34 KB)
    __shared__ float s_mol[4][HIDD];                   // per-wm column sums of gelu out
    __shared__ float s_molv[HIDD];

    // ---- tiling ids
    const int wm      = wid & 3, wn = wid >> 2;
    const int lrow    = lane & 15, g4 = lane >> 4;
    const int arow    = (wm << 4) + lrow;
    const int colbase = (wn << 5) + lrow;

    // ---- GEMV ids + tail ids
    const int gcol = tid & 127, kc = tid >> 7;         // kc in [0,8)
    const int colT = tid >> 1, kh = tid & 1;

    // ---- gauss recurrence ids: thread = (row, g-chunk, j-quarter)
    const int grow = tid >> 4;          // row i in [0,64)
    const int gch  = (tid >> 2) & 3;    // 16-center chunk
    const int jq   = tid & 3;           // 16-j quarter

    // ---- small preloads
    const float bo_r = bo[colT];
    const float b1a  = b1[colbase];
    const float b1b  = b1[colbase + 16];
    const float b2r  = b2[gcol];
    const float c0   = centers[gch << 4];   // chunk base center (input-exact)

    // ---- issue W1 loads early (indices recomputed inline)
    float w1v[16];
#pragma unroll
    for (int a = 0; a < 2; ++a) {
        const int slot = (a << 10) + tid;
        const int fg = slot >> 6, ls = slot & 63;
        const int k0 = ((fg >> 3) << 5) + ((ls >> 4) << 3);
        const int n  = ((fg & 7) << 4) + (ls & 15);
        const float* src = W1 + (size_t)k0 * HIDD + n;
#pragma unroll
        for (int r = 0; r < 8; ++r) w1v[a * 8 + r] = src[(size_t)r * HIDD];
    }

    // ---- coords + embedding
    const float* cbase = coords + (size_t)b * NA * 3;
    const float cx = cbase[lane * 3 + 0];
    const float cy = cbase[lane * 3 + 1];
    const float cz = cbase[lane * 3 + 2];
    {
        const int i = tid >> 4, e4 = (tid & 15) << 2;
        const int z = atomic_nums[b * NA + i];
        const float4 ev = *(const float4*)(embed_table + (size_t)z * EMBD + e4);
        short4 h4, l4;
        const float v[4] = {ev.x, ev.y, ev.z, ev.w};
        short* hp = (short*)&h4; short* lp = (short*)&l4;
#pragma unroll
        for (int q = 0; q < 4; ++q) {
            const unsigned short h = bf16_rne(v[q]);
            hp[q] = (short)h;
            lp[q] = (short)bf16_rne(v[q] - __uint_as_float((unsigned)h << 16));
        }
        *(short4*)&s_fhi[i][e4] = h4;
        *(short4*)&s_flo[i][e4] = l4;
    }

    // ---- pairwise distances: wave w writes rows 4w..4w+3 — exactly the rows its
    // own gauss threads (grow = tid>>4) read  =>  within-wave dep, no barrier
#pragma unroll
    for (int it = 0; it < 4; ++it) {
        const int i = (wid << 2) + it;
        const float xi = __shfl(cx, i, 64);
        const float yi = __shfl(cy, i, 64);
        const float zi = __shfl(cz, i, 64);
        const float dx = xi - cx, dy = yi - cy, dz = zi - cz;
        const float sq = dx * dx + dy * dy + dz * dz;
        s_dist[i * DSTR + lane] = sq > 0.0f ? sqrtf(sq) : 0.0f;
    }

    // ---- convert W1 -> s_w (hi only, b128 stores); w1v dies here
#pragma unroll
    for (int a = 0; a < 2; ++a) {
        unsigned Hu[4];
#pragma unroll
        for (int p = 0; p < 4; ++p) {
            const float x = w1v[a * 8 + 2 * p], y = w1v[a * 8 + 2 * p + 1];
            unsigned h;
            asm("v_cvt_pk_bf16_f32 %0, %1, %2" : "=v"(h) : "v"(x), "v"(y));
            Hu[p] = h;
        }
        const int slot = (a << 10) + tid;
        const int base = ((slot >> 6) << 9) + (slot & 63) * 8;
        *(uint4*)&s_w[base] = make_uint4(Hu[0], Hu[1], Hu[2], Hu[3]);
    }

    // ---- gaussian smear, 2 ops/term:
    // t_g = exp(-2(x-g*d)^2) = A * r^g * P_g with A = exp2(K2L*x^2),
    // r = exp2(UA*x), P_g = exp(-2 g^2 d^2) compile-time (hoisted to SGPRs).
    // s-chain: s *= r; acc_g = fma(s, P_g, acc_g). Same flush-to-zero
    // behavior as the R8 chain (A underflow only when max true term < 1e-15).
    {
        constexpr float L2E   = 1.4426950408889634f;
        constexpr float DELTA = 10.0f / 63.0f;
        constexpr float K2L   = -2.0f * L2E;
        constexpr float UA    = 4.0f * DELTA * L2E;
        const float P1  = 0.95085835f,  P2  = 0.81745274f, P3  = 0.63539088f,
                    P4  = 0.44653019f,  P5  = 0.28372112f, P6  = 0.16299117f,
                    P7  = 0.08465801f,  P8  = 0.03975530f, P9  = 0.01688004f,
                    P10 = 0.00647989f,  P11 = 0.00224901f, P12 = 0.00070576f,
                    P13 = 0.00020024f,  P14 = 5.136543e-5f, P15 = 1.191313e-5f;

        float acc[16];
#pragma unroll
        for (int q = 0; q < 16; ++q) acc[q] = 0.0f;

        const float* drow = &s_dist[grow * DSTR + (jq << 4)];
#pragma unroll
        for (int j4 = 0; j4 < 4; ++j4) {
            const float4 d4 = *(const float4*)(drow + (j4 << 2));
            const float dv[4] = {d4.x, d4.y, d4.z, d4.w};
#pragma unroll
            for (int jj = 0; jj < 4; ++jj) {
                const float x = dv[jj] - c0;
                float s = __builtin_amdgcn_exp2f(K2L * x * x);
                const float r = __builtin_amdgcn_exp2f(UA * x);
                acc[0] += s;
                s *= r; acc[1]  = fmaf(s, P1,  acc[1]);
                s *= r; acc[2]  = fmaf(s, P2,  acc[2]);
                s *= r; acc[3]  = fmaf(s, P3,  acc[3]);
                s *= r; acc[4]  = fmaf(s, P4,  acc[4]);
                s *= r; acc[5]  = fmaf(s, P5,  acc[5]);
                s *= r; acc[6]  = fmaf(s, P6,  acc[6]);
                s *= r; acc[7]  = fmaf(s, P7,  acc[7]);
                s *= r; acc[8]  = fmaf(s, P8,  acc[8]);
                s *= r; acc[9]  = fmaf(s, P9,  acc[9]);
                s *= r; acc[10] = fmaf(s, P10, acc[10]);
                s *= r; acc[11] = fmaf(s, P11, acc[11]);
                s *= r; acc[12] = fmaf(s, P12, acc[12]);
                s *= r; acc[13] = fmaf(s, P13, acc[13]);
                s *= r; acc[14] = fmaf(s, P14, acc[14]);
                s *= r; acc[15] = fmaf(s, P15, acc[15]);
            }
        }
        // reduce over j-quarters (lane bits 0-1)
#pragma unroll
        for (int q = 0; q < 16; ++q) {
            acc[q] += __shfl_xor(acc[q], 1, 64);
            acc[q] += __shfl_xor(acc[q], 2, 64);
        }
        if (jq == 0) {
            unsigned* hp = (unsigned*)&s_fhi[grow][EMBD + (gch << 4)];
            unsigned* lp = (unsigned*)&s_flo[grow][EMBD + (gch << 4)];
#pragma unroll
            for (int q2 = 0; q2 < 8; ++q2) {
                const float v0 = acc[2 * q2]     * (1.0f / 64.0f);
                const float v1 = acc[2 * q2 + 1] * (1.0f / 64.0f);
                const unsigned h0 = bf16_rne(v0), h1 = bf16_rne(v1);
                const unsigned l0 = bf16_rne(v0 - __uint_as_float(h0 << 16));
                const unsigned l1 = bf16_rne(v1 - __uint_as_float(h1 << 16));
                hp[q2] = h0 | (h1 << 16);
                lp[q2] = l0 | (l1 << 16);
            }
        }
    }
    __syncthreads();                                   // barrier 1: feat + W1 frags ready

    // ---- stage 3: G = gelu(feat @ W1 + b1); 2-term MFMA; col-sums folded in-register
    float wo_a[32];
    float w2r[16];
    {
        floatx4 acc0 = {0,0,0,0}, acc1 = {0,0,0,0};
#pragma unroll
        for (int ks = 0; ks < 4; ++ks) {
            const int k0 = (ks << 5) + (g4 << 3);
            const bfrag8 ahi = *(const bfrag8*)&s_fhi[arow][k0];
            const bfrag8 alo = *(const bfrag8*)&s_flo[arow][k0];
#pragma unroll
            for (int nt = 0; nt < 2; ++nt) {
                const int base = ((((ks << 3) + (wn << 1) + nt) << 6) + lane) << 3;
                const bfrag8 bhi = *(const bfrag8*)&s_w[base];
                floatx4 a = nt ? acc1 : acc0;
                a = __builtin_amdgcn_mfma_f32_16x16x32_bf16(ahi, bhi, a, 0, 0, 0);
                a = __builtin_amdgcn_mfma_f32_16x16x32_bf16(alo, bhi, a, 0, 0, 0);
                if (nt) acc1 = a; else acc0 = a;
            }
        }

        // issue first Wo half + W2 GEMV rows (hidden under gelu/reduce/barrier)
        {
            const float* wop = Wo + ((size_t)(kh << 6)) * OUTD + colT;
#pragma unroll
            for (int k = 0; k < 32; ++k) wo_a[k] = wop[(size_t)k * OUTD];
            const float* src = W2 + (size_t)(kc << 4) * HIDD + gcol;
#pragma unroll
            for (int q = 0; q < 16; ++q) w2r[q] = src[(size_t)q * HIDD];
        }

        // gelu + column reduce: rows g4*4+r summed in-lane, then across g4 groups
#pragma unroll
        for (int nt = 0; nt < 2; ++nt) {
            const float bb = nt ? b1b : b1a;
            const floatx4 a = nt ? acc1 : acc0;
            float s = gelu_fast(a[0] + bb) + gelu_fast(a[1] + bb)
                    + gelu_fast(a[2] + bb) + gelu_fast(a[3] + bb);
            s += __shfl_xor(s, 16, 64);
            s += __shfl_xor(s, 32, 64);
            if (lane < 16) s_mol[wm][colbase + (nt << 4)] = s;   // col-sum of 16 rows
        }
    }
    __syncthreads();                                   // barrier 2: s_mol ready

    // ---- GEMV: mol_raw[col] = sum_k (sum_wm s_mol[wm][k]) * W2[k][col]
    float wo_b[32];
    {
        float acc = 0.0f;
        const int kb = kc << 4;
#pragma unroll
        for (int q = 0; q < 16; ++q) {
            const int k = kb + q;
            const float hk = (s_mol[0][k] + s_mol[1][k])
                           + (s_mol[2][k] + s_mol[3][k]);   // wave-uniform broadcasts
            acc = fmaf(hk, w2r[q], acc);
        }
        s_dist[(kc << 7) + gcol] = acc;                // s_dist reused as partial buf

        // issue second Wo half (hidden under barrier 3 + reduce + barrier 4)
        const float* wop = Wo + ((size_t)((kh << 6) + 32)) * OUTD + colT;
#pragma unroll
        for (int k = 0; k < 32; ++k) wo_b[k] = wop[(size_t)k * OUTD];
    }
    __syncthreads();                                   // barrier 3: partials ready

    // ---- mol = colsum/64 + b2
    if (tid < HIDD) {
        float m = 0.0f;
#pragma unroll
        for (int p = 0; p < 8; ++p) m += s_dist[(p << 7) + tid];
        s_molv[tid] = m * (1.0f / 64.0f) + b2r;
    }
    __syncthreads();                                   // barrier 4: molv ready

    // ---- tail: out = mol @ Wo + bo; lane-pair K-split, shfl combine
    {
        const float* mp = &s_molv[kh << 6];
        float a = 0.0f;
#pragma unroll
        for (int k = 0; k < 32; ++k) a = fmaf(mp[k], wo_a[k], a);
#pragma unroll
        for (int k = 0; k < 32; ++k) a = fmaf(mp[32 + k], wo_b[k], a);
        a += __shfl_xor(a, 1, 64);
        if (kh == 0)
            out[(size_t)b * OUTD + colT] = a + bo_r;
    }
}
} // namespace

extern "C" void kernel_launch(void* const* d_in, const int* in_sizes, int n_in,
                              void* d_out, int out_size, void* d_ws, size_t ws_size,
                              hipStream_t stream) {
    const int*   atomic_nums = (const int*)  d_in[0];
    const float* coords      = (const float*)d_in[1];
    const float* embed_table = (const float*)d_in[2];
    const float* W1          = (const float*)d_in[3];
    const float* b1          = (const float*)d_in[4];
    const float* W2          = (const float*)d_in[5];
    const float* b2          = (const float*)d_in[6];
    const float* Wo          = (const float*)d_in[7];
    const float* bo          = (const float*)d_in[8];
    const float* centers     = (const float*)d_in[9];
    float*       out         = (float*)d_out;

    mlip_fused<<<NB, 1024, 0, stream>>>(atomic_nums, coords, embed_table,
                                        W1, b1, W2, b2, Wo, bo, centers, out);
}